// Round 1
// baseline (330.276 us; speedup 1.0000x reference)
//
#include <hip/hip_runtime.h>
#include <math.h>

#define CDIM 32
#define HWDIM 2304          // 48*48
#define BDIM 16
#define PIX 16              // pixels per block (one 64B line of the pixel axis)
#define NTHREADS 512
#define ROWSTR 33           // LDS row stride (32 + 1 pad)
#define PIXSTR 265          // LDS pixel stride for chunk buffer (8*33 + 1)
#define ZOFF (BDIM * CDIM * HWDIM)   // 1179648 floats of z, then 16 logdet

// out[ZOFF + b] must exist before the solve kernel atomically subtracts the
// per-block weight-logdet partial sums; harness poisons d_out each call.
__global__ void ld_init_kernel(const float* __restrict__ logdet,
                               float* __restrict__ out) {
    int b = threadIdx.x;
    if (b < BDIM) out[ZOFF + b] = logdet[b];
}

__global__ __launch_bounds__(NTHREADS, 4)
void solve_kernel(const float* __restrict__ input,
                  const float* __restrict__ weight,
                  float* __restrict__ out) {
    __shared__ float lds_w[PIX * PIXSTR];  // 16.9 KB: one 8-row chunk, 16 pixels
    __shared__ float lds_x[PIX * ROWSTR];  // 2.1 KB: rhs staging, reused for z
    __shared__ float lds_ld[PIX];

    const int t    = threadIdx.x;
    const int lane = t & 63;
    const int wv   = t >> 6;               // wave 0..7
    const int row  = lane & 31;            // matrix row owned by this lane
    const int q    = (wv << 1) | (lane >> 5);  // local pixel 0..15

    const int blk  = blockIdx.x;
    const int b    = blk / (HWDIM / PIX);  // 144 blocks per batch image
    const int pix0 = (blk % (HWDIM / PIX)) * PIX;

    // ---- stage rhs x coalesced (64B segments), then read per-lane ----
    {
        int p = t & 15, i = t >> 4;        // 512 threads cover 16px * 32 rows
        lds_x[p * ROWSTR + i] =
            input[(size_t)b * CDIM * HWDIM + (size_t)i * HWDIM + pix0 + p];
    }
    __syncthreads();
    float x = lds_x[q * ROWSTR + row];

    // ---- stage the 32x32 matrix into registers via LDS chunks ----
    float A[CDIM];
    const float* wbase = weight + (size_t)b * (CDIM * CDIM) * HWDIM + pix0;

    #pragma unroll
    for (int c = 0; c < 4; ++c) {          // chunk c = matrix rows 8c..8c+7
        __syncthreads();                   // protect lds_w reuse
        #pragma unroll
        for (int it = 0; it < 2; ++it) {
            int flat = it * NTHREADS + t;  // 0..1023
            int c2l  = flat >> 2;          // 0..255 : local channel (lr*32+j)
            int pq   = flat & 3;           // pixel quad
            const float4 v = *reinterpret_cast<const float4*>(
                wbase + (size_t)(c * 256 + c2l) * HWDIM + pq * 4);
            int lr   = c2l >> 5;
            int j    = c2l & 31;
            int base = (pq * 4) * PIXSTR + lr * ROWSTR + j;
            lds_w[base]              = v.x;
            lds_w[base + PIXSTR]     = v.y;
            lds_w[base + 2 * PIXSTR] = v.z;
            lds_w[base + 3 * PIXSTR] = v.w;
        }
        __syncthreads();
        if ((row >> 3) == c) {
            int base = q * PIXSTR + (row & 7) * ROWSTR;
            #pragma unroll
            for (int j = 0; j < CDIM; ++j) A[j] = lds_w[base + j];
        }
    }

    // ---- Gauss-Jordan with partial pivoting; lane = row, 2 pixels/wave ----
    bool  done   = false;
    int   ksel   = 0;
    float logacc = 0.0f;

    #pragma unroll
    for (int k = 0; k < CDIM; ++k) {
        float v = done ? -1.0f : fabsf(A[k]);
        float vmax = v;
        #pragma unroll
        for (int off = 16; off >= 1; off >>= 1)
            vmax = fmaxf(vmax, __shfl_xor(vmax, off));
        unsigned long long mask = __ballot((v == vmax) && !done);
        unsigned hm = (unsigned)(mask >> (lane & 32));   // this half's 32 bits
        int p = (lane & 32) + (__ffs(hm) - 1);           // first argmax lane

        float pivot = __shfl(A[k], p);
        float r = 1.0f / pivot;
        logacc += __log2f(fabsf(pivot));

        bool isp = (lane == p);
        if (isp) { done = true; ksel = k; }
        float g   = isp ? r    : -(A[k] * r);
        float bet = isp ? 0.0f : 1.0f;
        #pragma unroll
        for (int j = k + 1; j < CDIM; ++j) {
            float shv = __shfl(A[j], p);
            A[j] = bet * A[j] + g * shv;   // pivot row: scale; others: eliminate
        }
        float shx = __shfl(x, p);
        x = bet * x + g * shx;
    }
    // row retired at step ksel => z[ksel] = x

    // ---- outputs: z via LDS for coalesced store; logdet via block atomic ----
    lds_x[q * ROWSTR + ksel] = x;          // safe: all lds_x reads were pre-barrier
    if (row == 0) lds_ld[q] = logacc * 0.69314718055994531f;
    __syncthreads();
    {
        int p = t & 15, k = t >> 4;
        out[(size_t)b * CDIM * HWDIM + (size_t)k * HWDIM + pix0 + p] =
            lds_x[p * ROWSTR + k];
    }
    if (t == 0) {
        float s = 0.0f;
        #pragma unroll
        for (int i = 0; i < PIX; ++i) s += lds_ld[i];
        atomicAdd(&out[ZOFF + b], -s);
    }
}

extern "C" void kernel_launch(void* const* d_in, const int* in_sizes, int n_in,
                              void* d_out, int out_size, void* d_ws, size_t ws_size,
                              hipStream_t stream) {
    const float* input  = (const float*)d_in[0];
    const float* weight = (const float*)d_in[1];
    const float* logdet = (const float*)d_in[2];
    float* out = (float*)d_out;

    ld_init_kernel<<<1, 64, 0, stream>>>(logdet, out);
    solve_kernel<<<BDIM * (HWDIM / PIX), NTHREADS, 0, stream>>>(input, weight, out);
}